// Round 5
// baseline (156.856 us; speedup 1.0000x reference)
//
#include <hip/hip_runtime.h>
#include <math.h>
#include <stdint.h>

typedef __attribute__((ext_vector_type(8))) short short8;
typedef __attribute__((ext_vector_type(4))) float floatx4;

#define LN_EPS 1e-5f
#define ATT_SCALE 0.17677669529663687f  // 32^-0.5

__device__ __constant__ float INVF[8] = {
    1.0f, 0.31622776601683794f, 0.1f, 0.031622776601683794f,
    0.01f, 0.0031622776601683794f, 0.001f, 0.00031622776601683794f};

__device__ inline unsigned short f2bf(float f) {
    unsigned u = __float_as_uint(f);
    u += 0x7fffu + ((u >> 16) & 1u);
    return (unsigned short)(u >> 16);
}

__device__ inline void gl_lds16(const unsigned short* g, unsigned short* l) {
    __builtin_amdgcn_global_load_lds(
        (const __attribute__((address_space(1))) void*)(uintptr_t)g,
        (__attribute__((address_space(3))) void*)(uintptr_t)l, 16, 0, 0);
}

// ---------------- prep: weights fp32 -> bf16 (packed stores) --------------
__global__ __launch_bounds__(256)
void prep_w(const float* __restrict__ wq, const float* __restrict__ wo,
            unsigned short* __restrict__ bq, unsigned short* __restrict__ bo) {
    int g = blockIdx.x * 256 + threadIdx.x;  // 65536 groups of 4
    const float* src;
    unsigned short* dst;
    if (g < 49152) { src = wq + (size_t)g * 4; dst = bq + (size_t)g * 4; }
    else { int h = g - 49152; src = wo + (size_t)h * 4; dst = bo + (size_t)h * 4; }
    float4 v = *(const float4*)src;
    uint2 o;
    o.x = (unsigned)f2bf(v.x) | ((unsigned)f2bf(v.y) << 16);
    o.y = (unsigned)f2bf(v.z) | ((unsigned)f2bf(v.w) << 16);
    *(uint2*)dst = o;
}

// ---------------- fused LN + QKV GEMM + rotary + attention + out GEMM -----
// One block per (b,x): 512 threads = 8 waves; wave w owns y-rows 16w..16w+15.
__global__ __launch_bounds__(512, 2)
void fused_kernel(const float* __restrict__ pair_act, const int* __restrict__ mask,
                  const float* __restrict__ gamma, const float* __restrict__ beta,
                  const unsigned short* __restrict__ Wqkv,
                  const unsigned short* __restrict__ Wout,
                  float* __restrict__ out) {
    // LDS map (bytes): [0,32768) A-staging then B-tiles; [32768,43008) Ks 128x40;
    // [43008,51712) Vt 32x136; [51712,61952) per-wave scratch 16x40.
    __shared__ __align__(16) unsigned char smem[61952];
    unsigned short* S16 = (unsigned short*)smem;
    unsigned short* Ks = (unsigned short*)(smem + 32768);
    unsigned short* Vt = (unsigned short*)(smem + 43008);

    int bx = blockIdx.x;
    int tid = threadIdx.x;
    int w = tid >> 6, lane = tid & 63, qd = lane >> 4, lo = lane & 15;
    unsigned short* Qscr = (unsigned short*)(smem + 51712) + w * 640;

    float tX = -1.0f + (2.0f / 127.0f) * (float)(bx & 127);

    // ---------- Phase 0: LayerNorm -> A-fragments in registers ----------
    short8 a_frag[8];
    #pragma unroll
    for (int p = 0; p < 2; ++p) {
        if (tid < 256) {
            int rl = tid >> 2, q0 = tid & 3;  // 4 threads per row, 64 elems each
            const float* src = pair_act + ((size_t)(bx * 128 + p * 64 + rl)) * 256;
            float4 v[16];
            float s = 0.f;
            #pragma unroll
            for (int u = 0; u < 16; ++u) {
                v[u] = *(const float4*)(src + q0 * 4 + u * 16);
                s += v[u].x + v[u].y + v[u].z + v[u].w;
            }
            s += __shfl_xor(s, 1);
            s += __shfl_xor(s, 2);
            float mean = s * (1.0f / 256.0f);
            float sq = 0.f;
            #pragma unroll
            for (int u = 0; u < 16; ++u) {
                float d0 = v[u].x - mean, d1 = v[u].y - mean;
                float d2 = v[u].z - mean, d3 = v[u].w - mean;
                sq += d0 * d0 + d1 * d1 + d2 * d2 + d3 * d3;
            }
            sq += __shfl_xor(sq, 1);
            sq += __shfl_xor(sq, 2);
            float rs = rsqrtf(sq * (1.0f / 256.0f) + LN_EPS);
            #pragma unroll
            for (int u = 0; u < 16; ++u) {
                float4 g4 = *(const float4*)(gamma + q0 * 4 + u * 16);
                float4 b4 = *(const float4*)(beta + q0 * 4 + u * 16);
                unsigned e0 = f2bf((v[u].x - mean) * rs * g4.x + b4.x);
                unsigned e1 = f2bf((v[u].y - mean) * rs * g4.y + b4.y);
                unsigned e2 = f2bf((v[u].z - mean) * rs * g4.z + b4.z);
                unsigned e3 = f2bf((v[u].w - mean) * rs * g4.w + b4.w);
                int c = 2 * u + (q0 >> 1);
                int half = q0 & 1;
                int ss = (c & ~7) | ((c & 7) ^ (rl & 7));
                uint2 pk = {e0 | (e1 << 16), e2 | (e3 << 16)};
                *(uint2*)&S16[rl * 256 + ss * 8 + half * 4] = pk;
            }
        }
        __syncthreads();
        if ((w >> 2) == p) {
            int rl = (w & 3) * 16 + lo;
            #pragma unroll
            for (int c = 0; c < 8; ++c) {
                int ci = 4 * c + qd;
                int ss = (ci & ~7) | ((ci & 7) ^ (rl & 7));
                a_frag[c] = *(const short8*)&S16[rl * 256 + ss * 8];
            }
        }
        __syncthreads();
    }

    // ---------- Phase 1: QKV GEMM (12 n-chunks of 64), rotary, pack ----------
    unsigned q_pk[4][4][2], k_pk[4][4][2], v_pk[4][4][2];
    #pragma unroll
    for (int nc = 0; nc < 12; ++nc) {
        // stage B-tile: Wqkv rows nc*64..+63, 256 k, swizzled
        #pragma unroll
        for (int i = 0; i < 4; ++i) {
            int rbase = i * 16 + w * 2;
            int row = rbase + (lane >> 5);
            int sl = lane & 31;
            int c = (sl & ~7) | ((sl & 7) ^ (row & 7));
            gl_lds16(Wqkv + (size_t)(nc * 64 + row) * 256 + c * 8, S16 + rbase * 256);
        }
        __syncthreads();
        floatx4 acc[4];
        #pragma unroll
        for (int t = 0; t < 4; ++t) acc[t] = (floatx4){0.f, 0.f, 0.f, 0.f};
        #pragma unroll
        for (int c = 0; c < 8; ++c) {
            #pragma unroll
            for (int t = 0; t < 4; ++t) {
                int rw = t * 16 + lo;
                int ci = 4 * c + qd;
                int ss = (ci & ~7) | ((ci & 7) ^ (rw & 7));
                short8 bf = *(const short8*)&S16[rw * 256 + ss * 8];
                acc[t] = __builtin_amdgcn_mfma_f32_16x16x32_bf16(a_frag[c], bf,
                                                                 acc[t], 0, 0, 0);
            }
        }
        __syncthreads();
        if (nc == 0 || nc == 4) {  // rotary on cols 0..31 of q / k (head 0)
            #pragma unroll
            for (int t = 0; t < 2; ++t) {
                int pi = (t * 16 + lo) >> 1;
                float invf = INVF[pi & 7];
                float sgn = (lo & 1) ? 1.0f : -1.0f;
                #pragma unroll
                for (int r = 0; r < 4; ++r) {
                    int y = 16 * w + qd * 4 + r;
                    float tp = (pi < 8) ? tX : (-1.0f + (2.0f / 127.0f) * (float)y);
                    float sn, cs;
                    __sincosf(tp * invf, &sn, &cs);
                    float vv = acc[t][r];
                    float pv = __shfl_xor(vv, 1);
                    acc[t][r] = vv * cs + sgn * pv * sn;
                }
            }
        }
        #pragma unroll
        for (int t = 0; t < 4; ++t) {
            unsigned p0 = (unsigned)f2bf(acc[t][0]) | ((unsigned)f2bf(acc[t][1]) << 16);
            unsigned p1 = (unsigned)f2bf(acc[t][2]) | ((unsigned)f2bf(acc[t][3]) << 16);
            if (nc < 4) { q_pk[nc][t][0] = p0; q_pk[nc][t][1] = p1; }
            else if (nc < 8) { k_pk[nc - 4][t][0] = p0; k_pk[nc - 4][t][1] = p1; }
            else { v_pk[nc - 8][t][0] = p0; v_pk[nc - 8][t][1] = p1; }
        }
    }

    // ---------- Phase 2: attention per head ----------
    float msel[8];
    #pragma unroll
    for (int nt = 0; nt < 8; ++nt)
        msel[nt] = mask[bx * 128 + nt * 16 + lo] ? 0.0f : 1.0f;

    unsigned o_pk[8][2][2];
    #pragma unroll
    for (int h = 0; h < 8; ++h) {
        int hc = h >> 1, tt0 = (h & 1) * 2;
        // scatter this wave's K,V strips for head h into shared Ks/Vt
        #pragma unroll
        for (int tt = 0; tt < 2; ++tt) {
            int t = tt0 + tt;
            #pragma unroll
            for (int r = 0; r < 4; ++r) {
                unsigned kv = (k_pk[hc][t][r >> 1] >> ((r & 1) * 16)) & 0xffffu;
                unsigned vv = (v_pk[hc][t][r >> 1] >> ((r & 1) * 16)) & 0xffffu;
                int key = 16 * w + qd * 4 + r;
                int d = tt * 16 + lo;
                Ks[key * 40 + d] = (unsigned short)kv;
                Vt[d * 136 + key] = (unsigned short)vv;
            }
        }
        __syncthreads();
        // Q C-layout -> A-frag via wave-private scratch
        #pragma unroll
        for (int tt = 0; tt < 2; ++tt) {
            int t = tt0 + tt;
            #pragma unroll
            for (int r = 0; r < 4; ++r) {
                unsigned qv = (q_pk[hc][t][r >> 1] >> ((r & 1) * 16)) & 0xffffu;
                Qscr[(qd * 4 + r) * 40 + tt * 16 + lo] = (unsigned short)qv;
            }
        }
        short8 aq = *(const short8*)&Qscr[lo * 40 + qd * 8];
        // S = Q K^T, masked exp
        float ef[8][4];
        float sums[4] = {0.f, 0.f, 0.f, 0.f};
        #pragma unroll
        for (int nt = 0; nt < 8; ++nt) {
            short8 bk = *(const short8*)&Ks[(nt * 16 + lo) * 40 + qd * 8];
            floatx4 c = (floatx4){0.f, 0.f, 0.f, 0.f};
            c = __builtin_amdgcn_mfma_f32_16x16x32_bf16(aq, bk, c, 0, 0, 0);
            #pragma unroll
            for (int r = 0; r < 4; ++r) {
                float e = __expf(c[r] * ATT_SCALE) * msel[nt];
                ef[nt][r] = e;
                sums[r] += e;
            }
        }
        float inv[4];
        #pragma unroll
        for (int r = 0; r < 4; ++r) {
            float v = sums[r];
            v += __shfl_xor(v, 1);
            v += __shfl_xor(v, 2);
            v += __shfl_xor(v, 4);
            v += __shfl_xor(v, 8);
            inv[r] = 1.0f / v;
        }
        // O = P V, P round-trips through wave scratch per 32-key chunk
        floatx4 o[2];
        o[0] = (floatx4){0.f, 0.f, 0.f, 0.f};
        o[1] = (floatx4){0.f, 0.f, 0.f, 0.f};
        #pragma unroll
        for (int c2 = 0; c2 < 4; ++c2) {
            #pragma unroll
            for (int half = 0; half < 2; ++half) {
                int nt = c2 * 2 + half;
                #pragma unroll
                for (int r = 0; r < 4; ++r)
                    Qscr[(qd * 4 + r) * 40 + half * 16 + lo] = f2bf(ef[nt][r]);
            }
            short8 pa = *(const short8*)&Qscr[lo * 40 + qd * 8];
            #pragma unroll
            for (int n = 0; n < 2; ++n) {
                short8 vb = *(const short8*)&Vt[(n * 16 + lo) * 136 + c2 * 32 + qd * 8];
                o[n] = __builtin_amdgcn_mfma_f32_16x16x32_bf16(pa, vb, o[n], 0, 0, 0);
            }
        }
        #pragma unroll
        for (int n = 0; n < 2; ++n) {
            o_pk[h][n][0] = (unsigned)f2bf(o[n][0] * inv[0]) |
                            ((unsigned)f2bf(o[n][1] * inv[1]) << 16);
            o_pk[h][n][1] = (unsigned)f2bf(o[n][2] * inv[2]) |
                            ((unsigned)f2bf(o[n][3] * inv[3]) << 16);
        }
        __syncthreads();  // protect Ks/Vt before next head overwrites
    }

    // ---------- Phase 3: out GEMM (O[128x256] @ Wout^T) ----------
    // transform O to A-frags (k-chunk h = head h)
    short8 of[8];
    #pragma unroll
    for (int h = 0; h < 8; ++h) {
        #pragma unroll
        for (int tt = 0; tt < 2; ++tt)
            #pragma unroll
            for (int r = 0; r < 4; ++r) {
                unsigned ov = (o_pk[h][tt][r >> 1] >> ((r & 1) * 16)) & 0xffffu;
                Qscr[(qd * 4 + r) * 40 + tt * 16 + lo] = (unsigned short)ov;
            }
        of[h] = *(const short8*)&Qscr[lo * 40 + qd * 8];
    }
    #pragma unroll
    for (int nc = 0; nc < 4; ++nc) {
        #pragma unroll
        for (int i = 0; i < 4; ++i) {
            int rbase = i * 16 + w * 2;
            int row = rbase + (lane >> 5);
            int sl = lane & 31;
            int c = (sl & ~7) | ((sl & 7) ^ (row & 7));
            gl_lds16(Wout + (size_t)(nc * 64 + row) * 256 + c * 8, S16 + rbase * 256);
        }
        __syncthreads();
        floatx4 acc[4];
        #pragma unroll
        for (int t = 0; t < 4; ++t) acc[t] = (floatx4){0.f, 0.f, 0.f, 0.f};
        #pragma unroll
        for (int c = 0; c < 8; ++c) {
            #pragma unroll
            for (int t = 0; t < 4; ++t) {
                int rw = t * 16 + lo;
                int ci = 4 * c + qd;
                int ss = (ci & ~7) | ((ci & 7) ^ (rw & 7));
                short8 bf = *(const short8*)&S16[rw * 256 + ss * 8];
                acc[t] = __builtin_amdgcn_mfma_f32_16x16x32_bf16(of[c], bf,
                                                                 acc[t], 0, 0, 0);
            }
        }
        #pragma unroll
        for (int t = 0; t < 4; ++t)
            #pragma unroll
            for (int r = 0; r < 4; ++r)
                out[(size_t)(bx * 128 + 16 * w + qd * 4 + r) * 256 + nc * 64 +
                    t * 16 + lo] = acc[t][r];
        __syncthreads();
    }
}

extern "C" void kernel_launch(void* const* d_in, const int* in_sizes, int n_in,
                              void* d_out, int out_size, void* d_ws, size_t ws_size,
                              hipStream_t stream) {
    const float* pair_act = (const float*)d_in[0];
    const int* pair_mask = (const int*)d_in[1];
    const float* ln_gamma = (const float*)d_in[2];
    const float* ln_beta = (const float*)d_in[3];
    const float* Wqkv = (const float*)d_in[4];
    const float* Wout = (const float*)d_in[5];
    float* out = (float*)d_out;

    char* ws = (char*)d_ws;
    unsigned short* wqkv_bf = (unsigned short*)ws;            // 393,216 B
    unsigned short* wout_bf = (unsigned short*)(ws + 393216); // 131,072 B

    prep_w<<<256, 256, 0, stream>>>(Wqkv, Wout, wqkv_bf, wout_bf);
    fused_kernel<<<256, 512, 0, stream>>>(pair_act, pair_mask, ln_gamma, ln_beta,
                                          wqkv_bf, wout_bf, out);
}

// Round 6
// 138.920 us; speedup vs baseline: 1.1291x; 1.1291x over previous
//
#include <hip/hip_runtime.h>
#include <math.h>
#include <stdint.h>

typedef __attribute__((ext_vector_type(8))) short short8;
typedef __attribute__((ext_vector_type(4))) float floatx4;

#define LN_EPS 1e-5f
#define ATT_SCALE 0.17677669529663687f  // 32^-0.5

__device__ __constant__ float INVF[8] = {
    1.0f, 0.31622776601683794f, 0.1f, 0.031622776601683794f,
    0.01f, 0.0031622776601683794f, 0.001f, 0.00031622776601683794f};

__device__ inline unsigned short f2bf(float f) {
    unsigned u = __float_as_uint(f);
    u += 0x7fffu + ((u >> 16) & 1u);
    return (unsigned short)(u >> 16);
}

__device__ inline void gl_lds16(const unsigned short* g, unsigned short* l) {
    __builtin_amdgcn_global_load_lds(
        (const __attribute__((address_space(1))) void*)(uintptr_t)g,
        (__attribute__((address_space(3))) void*)(uintptr_t)l, 16, 0, 0);
}

// ---------------- prep: weights fp32 -> bf16 (packed stores) --------------
__global__ __launch_bounds__(256)
void prep_w(const float* __restrict__ wq, const float* __restrict__ wo,
            unsigned short* __restrict__ bq, unsigned short* __restrict__ bo) {
    int g = blockIdx.x * 256 + threadIdx.x;  // 65536 groups of 4
    const float* src;
    unsigned short* dst;
    if (g < 49152) { src = wq + (size_t)g * 4; dst = bq + (size_t)g * 4; }
    else { int h = g - 49152; src = wo + (size_t)h * 4; dst = bo + (size_t)h * 4; }
    float4 v = *(const float4*)src;
    uint2 o;
    o.x = (unsigned)f2bf(v.x) | ((unsigned)f2bf(v.y) << 16);
    o.y = (unsigned)f2bf(v.z) | ((unsigned)f2bf(v.w) << 16);
    *(uint2*)dst = o;
}

// ---------------- fused kernel: one block per (b,x), 512 thr = 8 waves ----
__global__ __launch_bounds__(512, 2)
void fused_kernel(const float* __restrict__ pair_act, const int* __restrict__ mask,
                  const float* __restrict__ gamma, const float* __restrict__ beta,
                  const unsigned short* __restrict__ Wqkv,
                  const unsigned short* __restrict__ Wout,
                  float* __restrict__ out) {
    // S16: 32 KB, reused as (a) LN exchange 128x128 bf16, (b) B-tiles 64x256.
    __shared__ __align__(16) unsigned short S16[16384];
    __shared__ __align__(16) unsigned short Ks[128 * 40];
    __shared__ __align__(16) unsigned short Vt[32 * 136];
    __shared__ __align__(16) unsigned short Qall[8 * 640];

    int bx = blockIdx.x;
    int tid = threadIdx.x;
    int w = tid >> 6, lane = tid & 63, qd = lane >> 4, lo = lane & 15;
    unsigned short* Qscr = Qall + w * 640;

    float tX = -1.0f + (2.0f / 127.0f) * (float)(bx & 127);

    float msel[8];
    #pragma unroll
    for (int nt = 0; nt < 8; ++nt)
        msel[nt] = mask[bx * 128 + nt * 16 + lo] ? 0.0f : 1.0f;

    // ---------- Phase 0: LayerNorm, all 512 threads; 2 column-half passes --
    short8 a_frag[8];
    {
        int rl = tid >> 2, q0 = tid & 3;  // row 0..127, quarter 0..3
        const float* src = pair_act + ((size_t)(bx * 128 + rl)) * 256 + q0 * 4;
        float4 v[16];
        float s = 0.f;
        #pragma unroll
        for (int u = 0; u < 16; ++u) {
            v[u] = *(const float4*)(src + u * 16);
            s += v[u].x + v[u].y + v[u].z + v[u].w;
        }
        s += __shfl_xor(s, 1);
        s += __shfl_xor(s, 2);
        float mean = s * (1.0f / 256.0f);
        float sq = 0.f;
        #pragma unroll
        for (int u = 0; u < 16; ++u) {
            float d0 = v[u].x - mean, d1 = v[u].y - mean;
            float d2 = v[u].z - mean, d3 = v[u].w - mean;
            sq += d0 * d0 + d1 * d1 + d2 * d2 + d3 * d3;
        }
        sq += __shfl_xor(sq, 1);
        sq += __shfl_xor(sq, 2);
        float rs = rsqrtf(sq * (1.0f / 256.0f) + LN_EPS);

        int rw = 16 * w + lo;
        #pragma unroll
        for (int p = 0; p < 2; ++p) {
            #pragma unroll
            for (int ul = 0; ul < 8; ++ul) {
                int u = p * 8 + ul;
                float4 g4 = *(const float4*)(gamma + q0 * 4 + u * 16);
                float4 b4 = *(const float4*)(beta + q0 * 4 + u * 16);
                unsigned e0 = f2bf((v[u].x - mean) * rs * g4.x + b4.x);
                unsigned e1 = f2bf((v[u].y - mean) * rs * g4.y + b4.y);
                unsigned e2 = f2bf((v[u].z - mean) * rs * g4.z + b4.z);
                unsigned e3 = f2bf((v[u].w - mean) * rs * g4.w + b4.w);
                int cw = 2 * ul + (q0 >> 1);
                int ss = (cw & ~7) | ((cw & 7) ^ (rl & 7));
                uint2 pk;
                pk.x = e0 | (e1 << 16);
                pk.y = e2 | (e3 << 16);
                *(uint2*)&S16[rl * 128 + ss * 8 + (q0 & 1) * 4] = pk;
            }
            __syncthreads();
            #pragma unroll
            for (int cp = 0; cp < 4; ++cp) {
                int ci = cp * 4 + qd;
                int ss = (ci & ~7) | ((ci & 7) ^ (rw & 7));
                a_frag[p * 4 + cp] = *(const short8*)&S16[rw * 128 + ss * 8];
            }
            __syncthreads();
        }
    }

    // ---------- Phase 1+2: per 64-col chunk: q,k,v GEMM -> attention -------
    short8 of[8];  // out-GEMM A-fragments, one per head
    #pragma unroll
    for (int hc = 0; hc < 4; ++hc) {
        unsigned q_pk[4][2], k_pk[4][2], v_pk[4][2];
        #pragma unroll
        for (int part = 0; part < 3; ++part) {  // 0=q, 1=k, 2=v
            if (hc != 0 || part != 0) __syncthreads();  // S16 readers done
            // stage Wqkv rows [part*256 + hc*64, +64)
            const unsigned short* Wsrc = Wqkv + (size_t)(part * 256 + hc * 64) * 256;
            #pragma unroll
            for (int i = 0; i < 4; ++i) {
                int rbase = i * 16 + w * 2;
                int row = rbase + (lane >> 5);
                int sl = lane & 31;
                int c = (sl & ~7) | ((sl & 7) ^ (row & 7));
                gl_lds16(Wsrc + (size_t)row * 256 + c * 8, S16 + rbase * 256);
            }
            __syncthreads();
            floatx4 acc[4];
            #pragma unroll
            for (int t = 0; t < 4; ++t) acc[t] = (floatx4){0.f, 0.f, 0.f, 0.f};
            #pragma unroll
            for (int cc = 0; cc < 8; ++cc) {
                #pragma unroll
                for (int t = 0; t < 4; ++t) {
                    int rw2 = t * 16 + lo;
                    int ci = cc * 4 + qd;
                    int ss = (ci & ~7) | ((ci & 7) ^ (rw2 & 7));
                    short8 bf = *(const short8*)&S16[rw2 * 256 + ss * 8];
                    acc[t] = __builtin_amdgcn_mfma_f32_16x16x32_bf16(
                        a_frag[cc], bf, acc[t], 0, 0, 0);
                }
            }
            if (hc == 0 && part < 2) {  // rotary on cols 0..31 of q and k
                #pragma unroll
                for (int t = 0; t < 2; ++t) {
                    int pi = (t * 16 + lo) >> 1;
                    float invf = INVF[pi & 7];
                    float sgn = (lo & 1) ? 1.0f : -1.0f;
                    #pragma unroll
                    for (int r = 0; r < 4; ++r) {
                        int y = 16 * w + qd * 4 + r;
                        float tp = (pi < 8) ? tX
                                            : (-1.0f + (2.0f / 127.0f) * (float)y);
                        float sn, cs;
                        __sincosf(tp * invf, &sn, &cs);
                        float vv = acc[t][r];
                        float pv = __shfl_xor(vv, 1);
                        acc[t][r] = vv * cs + sgn * pv * sn;
                    }
                }
            }
            #pragma unroll
            for (int t = 0; t < 4; ++t) {
                unsigned p0 = (unsigned)f2bf(acc[t][0]) |
                              ((unsigned)f2bf(acc[t][1]) << 16);
                unsigned p1 = (unsigned)f2bf(acc[t][2]) |
                              ((unsigned)f2bf(acc[t][3]) << 16);
                if (part == 0) { q_pk[t][0] = p0; q_pk[t][1] = p1; }
                else if (part == 1) { k_pk[t][0] = p0; k_pk[t][1] = p1; }
                else { v_pk[t][0] = p0; v_pk[t][1] = p1; }
            }
        }

        // ---- attention for heads 2hc, 2hc+1 ----
        #pragma unroll
        for (int sub = 0; sub < 2; ++sub) {
            int h = hc * 2 + sub, tt0 = sub * 2;
            __syncthreads();  // previous Ks/Vt readers done
            #pragma unroll
            for (int tt = 0; tt < 2; ++tt) {
                int t = tt0 + tt;
                int d = tt * 16 + lo;
                #pragma unroll
                for (int r = 0; r < 4; ++r) {
                    unsigned kv = (k_pk[t][r >> 1] >> ((r & 1) * 16)) & 0xffffu;
                    Ks[(16 * w + qd * 4 + r) * 40 + d] = (unsigned short)kv;
                }
                uint2 pv;
                pv.x = v_pk[t][0];
                pv.y = v_pk[t][1];
                *(uint2*)&Vt[d * 136 + 16 * w + qd * 4] = pv;
            }
            __syncthreads();
            // q C-layout -> A-frag via wave scratch
            #pragma unroll
            for (int tt = 0; tt < 2; ++tt) {
                int t = tt0 + tt;
                #pragma unroll
                for (int r = 0; r < 4; ++r) {
                    unsigned qv = (q_pk[t][r >> 1] >> ((r & 1) * 16)) & 0xffffu;
                    Qscr[(qd * 4 + r) * 40 + tt * 16 + lo] = (unsigned short)qv;
                }
            }
            short8 aq = *(const short8*)&Qscr[lo * 40 + qd * 8];
            float ef[8][4];
            float sums[4] = {0.f, 0.f, 0.f, 0.f};
            #pragma unroll
            for (int nt = 0; nt < 8; ++nt) {
                short8 bk = *(const short8*)&Ks[(nt * 16 + lo) * 40 + qd * 8];
                floatx4 c = (floatx4){0.f, 0.f, 0.f, 0.f};
                c = __builtin_amdgcn_mfma_f32_16x16x32_bf16(aq, bk, c, 0, 0, 0);
                #pragma unroll
                for (int r = 0; r < 4; ++r) {
                    float e = __expf(c[r] * ATT_SCALE) * msel[nt];
                    ef[nt][r] = e;
                    sums[r] += e;
                }
            }
            float inv[4];
            #pragma unroll
            for (int r = 0; r < 4; ++r) {
                float vv = sums[r];
                vv += __shfl_xor(vv, 1);
                vv += __shfl_xor(vv, 2);
                vv += __shfl_xor(vv, 4);
                vv += __shfl_xor(vv, 8);
                inv[r] = 1.0f / vv;
            }
            floatx4 o[2];
            o[0] = (floatx4){0.f, 0.f, 0.f, 0.f};
            o[1] = (floatx4){0.f, 0.f, 0.f, 0.f};
            #pragma unroll
            for (int c2 = 0; c2 < 4; ++c2) {
                #pragma unroll
                for (int half = 0; half < 2; ++half) {
                    int nt = c2 * 2 + half;
                    #pragma unroll
                    for (int r = 0; r < 4; ++r)
                        Qscr[(qd * 4 + r) * 40 + half * 16 + lo] = f2bf(ef[nt][r]);
                }
                short8 pa = *(const short8*)&Qscr[lo * 40 + qd * 8];
                #pragma unroll
                for (int n = 0; n < 2; ++n) {
                    short8 vb =
                        *(const short8*)&Vt[(n * 16 + lo) * 136 + c2 * 32 + qd * 8];
                    o[n] = __builtin_amdgcn_mfma_f32_16x16x32_bf16(pa, vb, o[n],
                                                                   0, 0, 0);
                }
            }
            // normalized O -> A-frag for out GEMM (k-chunk h)
            #pragma unroll
            for (int n = 0; n < 2; ++n)
                #pragma unroll
                for (int r = 0; r < 4; ++r)
                    Qscr[(qd * 4 + r) * 40 + n * 16 + lo] = f2bf(o[n][r] * inv[r]);
            of[h] = *(const short8*)&Qscr[lo * 40 + qd * 8];
        }
    }

    // ---------- Phase 3: out GEMM: out = O[128x256] @ Wout^T ----------
    #pragma unroll
    for (int nc = 0; nc < 4; ++nc) {
        __syncthreads();  // S16 free (attn barriers for nc=0; compute for nc>0)
        const unsigned short* Wsrc = Wout + (size_t)(nc * 64) * 256;
        #pragma unroll
        for (int i = 0; i < 4; ++i) {
            int rbase = i * 16 + w * 2;
            int row = rbase + (lane >> 5);
            int sl = lane & 31;
            int c = (sl & ~7) | ((sl & 7) ^ (row & 7));
            gl_lds16(Wsrc + (size_t)row * 256 + c * 8, S16 + rbase * 256);
        }
        __syncthreads();
        floatx4 acc[4];
        #pragma unroll
        for (int t = 0; t < 4; ++t) acc[t] = (floatx4){0.f, 0.f, 0.f, 0.f};
        #pragma unroll
        for (int cc = 0; cc < 8; ++cc) {
            #pragma unroll
            for (int t = 0; t < 4; ++t) {
                int rw2 = t * 16 + lo;
                int ci = cc * 4 + qd;
                int ss = (ci & ~7) | ((ci & 7) ^ (rw2 & 7));
                short8 bf = *(const short8*)&S16[rw2 * 256 + ss * 8];
                acc[t] = __builtin_amdgcn_mfma_f32_16x16x32_bf16(of[cc], bf,
                                                                 acc[t], 0, 0, 0);
            }
        }
        #pragma unroll
        for (int t = 0; t < 4; ++t)
            #pragma unroll
            for (int r = 0; r < 4; ++r)
                out[(size_t)(bx * 128 + 16 * w + qd * 4 + r) * 256 + nc * 64 +
                    t * 16 + lo] = acc[t][r];
    }
}

extern "C" void kernel_launch(void* const* d_in, const int* in_sizes, int n_in,
                              void* d_out, int out_size, void* d_ws, size_t ws_size,
                              hipStream_t stream) {
    const float* pair_act = (const float*)d_in[0];
    const int* pair_mask = (const int*)d_in[1];
    const float* ln_gamma = (const float*)d_in[2];
    const float* ln_beta = (const float*)d_in[3];
    const float* Wqkv = (const float*)d_in[4];
    const float* Wout = (const float*)d_in[5];
    float* out = (float*)d_out;

    char* ws = (char*)d_ws;
    unsigned short* wqkv_bf = (unsigned short*)ws;            // 393,216 B
    unsigned short* wout_bf = (unsigned short*)(ws + 393216); // 131,072 B

    prep_w<<<256, 256, 0, stream>>>(Wqkv, Wout, wqkv_bf, wout_bf);
    fused_kernel<<<256, 512, 0, stream>>>(pair_act, pair_mask, ln_gamma, ln_beta,
                                          wqkv_bf, wout_bf, out);
}